// Round 16
// baseline (371.071 us; speedup 1.0000x reference)
//
#include <hip/hip_runtime.h>

namespace {
constexpr int H = 544, W = 960, D = 64, NB = 2;
constexpr long SL      = (long)H * W;     // per-batch image elems
constexpr long SLICE_B = (long)NB * SL * 4;
constexpr long W64     = (long)W * 64;    // row stride in out1 elems
}

// ===========================================================================
// Bitwise replica of XLA ReduceWindowRewriter base-16 cumsum (verified
// r12-r15). State at tile t = left-assoc fold of tile TOTALS:
//   base(t) = a==0 ? (c==0 ? 0 : o1p) : (c==0 ? o2 : o2+o1p), c=t%16, a=t/16
//   scan[16t+j] = base(t) + ip[j],  ip = sequential 16-elem prefix.
// box1d at e = q-14: scan(q) - (e==0 ? 0 : scan(q-15)).
// Two-phase per row/column: (A) per-wave tile totals -> LDS, (B) each wave
// replays the cheap scalar fold to its start state, recomputes the previous
// tile's scan values (lag window), then emits its tiles independently.
// All sums in identical order => bitwise identical to the serial scan.
// ===========================================================================

__device__ __forceinline__ void fold16(float& o1p, float& o2, int& c, int& a,
                                       float tot) {
  o1p = (c == 0) ? tot : (o1p + tot);
  if (++c == 16) { o2 = (a == 0) ? o1p : (o2 + o1p); ++a; c = 0; }
}
__device__ __forceinline__ float baseof(float o1p, float o2, int c, int a) {
  return (a == 0) ? ((c == 0) ? 0.f : o1p) : ((c == 0) ? o2 : (o2 + o1p));
}

// ---------------------------------------------------------------------------
// Phase 1: vertical box -> out1[b][y][x][d]. Block = (x, b), 4 waves; lane=d.
// Padded column length 558 = tiles 0..34 (34 full + partial 14).
// Wave w owns tiles [9w, 9w+9) (w<3) or [27, 35) (w=3).
// ---------------------------------------------------------------------------
__global__ __launch_bounds__(256) void vbox_p(
    const float* __restrict__ Lp, const float* __restrict__ Rp,
    float* __restrict__ out1) {
  __shared__ float T[35][64];
  const int lane = threadIdx.x & 63;
  const int w    = threadIdx.x >> 6;
  const int x = blockIdx.x;
  const int b = blockIdx.y;
  const int xs = max(x - lane, 0);                 // clip(x-d, 0, W-1)
  const float* Lc = Lp + (long)b * SL + x;
  const float* Rc = Rp + (long)b * SL + xs;
  float* Ob = out1 + ((long)b * H) * W64 + (long)x * 64 + lane;

  auto val = [&](int q) -> float {
    const int y = q - 7;
    return (y >= 0 && y < H) ? fabsf(Lc[(long)y * W] - Rc[(long)y * W]) : 0.f;
  };

  const int t0   = 9 * w;
  const int tend = (w < 3) ? (t0 + 9) : 35;

  // ---- phase A: owned-tile totals (identical 16-add order) ----
  for (int t = t0; t < tend; ++t) {
    float vv[16];
#pragma unroll
    for (int j = 0; j < 16; ++j) vv[j] = val(16 * t + j);
    float s = vv[0];
#pragma unroll
    for (int j = 1; j < 16; ++j) s += vv[j];
    T[t][lane] = s;
  }
  __syncthreads();

  // ---- phase B: replay fold to entry state ----
  float o1p = 0.f, o2 = 0.f;
  int c = 0, a = 0;
  for (int tp = 0; tp + 1 < t0; ++tp) fold16(o1p, o2, c, a, T[tp][lane]);

  float poc[16];
  if (w > 0) {                                     // recompute tile t0-1 scan
    const float base_prev = baseof(o1p, o2, c, a);
    fold16(o1p, o2, c, a, T[t0 - 1][lane]);
    float vv[16];
#pragma unroll
    for (int j = 0; j < 16; ++j) vv[j] = val(16 * (t0 - 1) + j);
    float ipp = vv[0];
    poc[0] = base_prev + ipp;
#pragma unroll
    for (int j = 1; j < 16; ++j) { ipp += vv[j]; poc[j] = base_prev + ipp; }
  }
  float base = baseof(o1p, o2, c, a);

  for (int t = t0; t < tend; ++t) {
    float vv[16];
#pragma unroll
    for (int j = 0; j < 16; ++j) vv[j] = val(16 * t + j);
    float oc_[16];
    float ip = vv[0];
    oc_[0] = base + ip;
#pragma unroll
    for (int j = 1; j < 16; ++j) { ip += vv[j]; oc_[j] = base + ip; }

    if (t == 0) {
      Ob[0]   = oc_[14];                           // e=0: lo = 0
      Ob[W64] = oc_[15] - oc_[0];                  // e=1
    } else if (t == 34) {                          // partial: emits 530..543
#pragma unroll
      for (int j = 0; j < 14; ++j)
        Ob[(long)(530 + j) * W64] = oc_[j] - poc[j + 1];
    } else {
#pragma unroll
      for (int j = 0; j < 16; ++j) {
        const float lo = (j < 15) ? poc[j + 1] : oc_[0];
        Ob[(long)(16 * t + j - 14) * W64] = oc_[j] - lo;
      }
    }
    if (t + 1 < tend) {
      fold16(o1p, o2, c, a, ip);
      base = baseof(o1p, o2, c, a);
#pragma unroll
      for (int j = 0; j < 16; ++j) poc[j] = oc_[j];
    }
  }
}

// ---------------------------------------------------------------------------
// Phase 2: horizontal box + argmin. Block = (y, b), 4 waves; lane = d.
// Padded row length 974 = tiles 0..60 (60 full + partial 14).
// Wave w owns tiles [0,16) / [16,31) / [31,46) / [46,61).
// Argmin: fmin butterfly (exact associative min) + ballot(cost==min) ->
// ffsll = smallest d (lane=d) = first-occurrence (verified r15).
// ---------------------------------------------------------------------------
__global__ __launch_bounds__(256) void hbox_p2(
    const float* __restrict__ out1, int* __restrict__ out) {
  __shared__ float T[61][64];
  const int lane = threadIdx.x & 63;
  const int w    = threadIdx.x >> 6;
  const int y = blockIdx.x, b = blockIdx.y;
  const float* __restrict__ rowp = out1 + ((long)(b * H + y)) * W64 + lane;
  int* __restrict__ orow = out + (long)b * SL + (long)y * W;

  auto val = [&](int q) -> float {
    const int xsrc = q - 7;
    return (xsrc >= 0 && xsrc < W) ? rowp[(long)xsrc * 64] : 0.f;
  };

  const int t0   = (w == 0) ? 0 : (16 + 15 * (w - 1));   // 0,16,31,46
  const int tend = t0 + ((w == 0) ? 16 : 15);

  // ---- phase A ----
  for (int t = t0; t < tend; ++t) {
    float vv[16];
#pragma unroll
    for (int j = 0; j < 16; ++j) vv[j] = val(16 * t + j);
    float s = vv[0];
#pragma unroll
    for (int j = 1; j < 16; ++j) s += vv[j];
    T[t][lane] = s;
  }
  __syncthreads();

  // ---- phase B ----
  float o1p = 0.f, o2 = 0.f;
  int c = 0, a = 0;
  for (int tp = 0; tp + 1 < t0; ++tp) fold16(o1p, o2, c, a, T[tp][lane]);

  float poc[16];
  if (w > 0) {
    const float base_prev = baseof(o1p, o2, c, a);
    fold16(o1p, o2, c, a, T[t0 - 1][lane]);
    float vv[16];
#pragma unroll
    for (int j = 0; j < 16; ++j) vv[j] = val(16 * (t0 - 1) + j);
    float ipp = vv[0];
    poc[0] = base_prev + ipp;
#pragma unroll
    for (int j = 1; j < 16; ++j) { ipp += vv[j]; poc[j] = base_prev + ipp; }
  }
  float base = baseof(o1p, o2, c, a);

  for (int t = t0; t < tend; ++t) {
    float vv[16];
#pragma unroll
    for (int j = 0; j < 16; ++j) vv[j] = val(16 * t + j);
    float oc_[16];
    float ip = vv[0];
    oc_[0] = base + ip;
#pragma unroll
    for (int j = 1; j < 16; ++j) { ip += vv[j]; oc_[j] = base + ip; }

    if (t == 0) {
      const float c0 = oc_[14], c1 = oc_[15] - oc_[0];   // e = 0, 1
      float m0 = c0, m1 = c1;
#pragma unroll
      for (int s = 0; s < 6; ++s) {
        const int off = 1 << s;
        m0 = fminf(m0, __shfl_xor(m0, off));
        m1 = fminf(m1, __shfl_xor(m1, off));
      }
      const int d0 = __ffsll((unsigned long long)__ballot(c0 == m0)) - 1;
      const int d1 = __ffsll((unsigned long long)__ballot(c1 == m1)) - 1;
      const int res = (lane == 0) ? d0 : d1;
      if (lane < 2) orow[lane] = res;
    } else if (t == 60) {                          // partial: e = 946..959
      float bc[14], mn[14];
#pragma unroll
      for (int j = 0; j < 14; ++j) { bc[j] = oc_[j] - poc[j + 1]; mn[j] = bc[j]; }
#pragma unroll
      for (int s = 0; s < 6; ++s) {
        const int off = 1 << s;
#pragma unroll
        for (int j = 0; j < 14; ++j) mn[j] = fminf(mn[j], __shfl_xor(mn[j], off));
      }
      int res = 0;
#pragma unroll
      for (int j = 0; j < 14; ++j) {
        const int dj = __ffsll((unsigned long long)__ballot(bc[j] == mn[j])) - 1;
        res = (lane == j) ? dj : res;
      }
      if (lane < 14) orow[946 + lane] = res;
    } else {
      float bc[16], mn[16];
#pragma unroll
      for (int j = 0; j < 16; ++j) {
        bc[j] = oc_[j] - ((j < 15) ? poc[j + 1] : oc_[0]);
        mn[j] = bc[j];
      }
#pragma unroll
      for (int s = 0; s < 6; ++s) {
        const int off = 1 << s;
#pragma unroll
        for (int j = 0; j < 16; ++j) mn[j] = fminf(mn[j], __shfl_xor(mn[j], off));
      }
      int res = 0;
#pragma unroll
      for (int j = 0; j < 16; ++j) {
        const int dj = __ffsll((unsigned long long)__ballot(bc[j] == mn[j])) - 1;
        res = (lane == j) ? dj : res;
      }
      if (lane < 16) orow[16 * t - 14 + lane] = res;
    }

    if (t + 1 < tend) {
      fold16(o1p, o2, c, a, ip);
      base = baseof(o1p, o2, c, a);
#pragma unroll
      for (int j = 0; j < 16; ++j) poc[j] = oc_[j];
    }
  }
}

extern "C" void kernel_launch(void* const* d_in, const int* in_sizes, int n_in,
                              void* d_out, int out_size, void* d_ws, size_t ws_size,
                              hipStream_t stream) {
  const float* L = (const float*)d_in[0];
  const float* R = (const float*)d_in[1];
  int* out = (int*)d_out;
  if (ws_size < (size_t)(D * SLICE_B)) return;   // direct path confirmed in r12
  float* out1 = (float*)d_ws;

  vbox_p<<<dim3(W, NB), 256, 0, stream>>>(L, R, out1);
  hbox_p2<<<dim3(H, NB), 256, 0, stream>>>(out1, out);
}

// Round 17
// 197.747 us; speedup vs baseline: 1.8765x; 1.8765x over previous
//
#include <hip/hip_runtime.h>

namespace {
constexpr int H = 544, W = 960, D = 64, NB = 2;
constexpr long SL      = (long)H * W;     // per-batch image elems
constexpr long SLICE_B = (long)NB * SL * 4;
constexpr long W64     = (long)W * 64;    // row stride in out1 elems
}

// ===========================================================================
// Bitwise replica of XLA ReduceWindowRewriter base-16 cumsum (verified
// r12-r16). State at tile t = left-assoc fold of tile TOTALS:
//   base(t) = a==0 ? (c==0 ? 0 : o1p) : (c==0 ? o2 : o2+o1p), c=t%16, a=t/16
//   scan[16t+j] = base(t) + ip[j],  ip = sequential 16-elem prefix.
// box1d at e = q-14: scan(q) - (e==0 ? 0 : scan(q-15)).
// ===========================================================================

__device__ __forceinline__ void fold16(float& o1p, float& o2, int& c, int& a,
                                       float tot) {
  o1p = (c == 0) ? tot : (o1p + tot);
  if (++c == 16) { o2 = (a == 0) ? o1p : (o2 + o1p); ++a; c = 0; }
}
__device__ __forceinline__ float baseof(float o1p, float o2, int c, int a) {
  return (a == 0) ? ((c == 0) ? 0.f : o1p) : ((c == 0) ? o2 : (o2 + o1p));
}

#define TILE_FULL()                                                          \
  {                                                                          \
    const float base =                                                       \
        (a == 0) ? ((c == 0) ? 0.f : o1p) : ((c == 0) ? o2 : (o2 + o1p));    \
    float ip = wc[0];                                                        \
    oc_[0] = base + ip;                                                      \
    _Pragma("unroll") for (int j = 1; j < 16; ++j) {                         \
      ip += wc[j];                                                           \
      oc_[j] = base + ip;                                                    \
    }                                                                        \
    o1p = (c == 0) ? ip : (o1p + ip);                                        \
    if (++c == 16) { o2 = (a == 0) ? o1p : (o2 + o1p); ++a; c = 0; }         \
  }

#define TILE_PART14()                                                        \
  {                                                                          \
    const float base =                                                       \
        (a == 0) ? ((c == 0) ? 0.f : o1p) : ((c == 0) ? o2 : (o2 + o1p));    \
    float ip = wc[0];                                                        \
    oc_[0] = base + ip;                                                      \
    _Pragma("unroll") for (int j = 1; j < 14; ++j) {                         \
      ip += wc[j];                                                           \
      oc_[j] = base + ip;                                                    \
    }                                                                        \
  }

#define ROT()                                                                \
  _Pragma("unroll") for (int j = 0; j < 16; ++j) {                           \
    op_[j] = oc_[j];                                                         \
    wc[j] = wn[j];                                                           \
  }

// ---------------------------------------------------------------------------
// Phase 1: vertical box -> out1[b][y][x][d]. Thread = (b, x, lane=d).
// Verbatim r13/r14 kernel (verified 74 us, write-BW-bound; lockstep y-advance
// keeps the write stream dense -- do NOT re-parallelize, r16 regression).
// ---------------------------------------------------------------------------
__global__ __launch_bounds__(256) void vbox_t(
    const float* __restrict__ Lp, const float* __restrict__ Rp,
    float* __restrict__ out1) {
  const int t  = blockIdx.x * 256 + threadIdx.x;
  const int dc = t & 63;
  const int rs = t >> 6;
  const int x  = rs % W;
  const int b  = rs / W;
  const int xs = max(x - dc, 0);
  const float* Lc = Lp + (long)b * SL + x;
  const float* Rc = Rp + (long)b * SL + xs;
  float* Ob = out1 + ((long)b * H) * W64 + (long)x * 64 + dc;

  float o1p = 0.f, o2 = 0.f;
  int c = 0, a = 0;
  float wc[16], wn[16], oc_[16], op_[16];

#pragma unroll
  for (int j = 0; j < 16; ++j) {
    const long yy = j - 7;
    wc[j] = (j >= 7) ? fabsf(Lc[yy * W] - Rc[yy * W]) : 0.f;
  }
#pragma unroll
  for (int j = 0; j < 16; ++j) {
    const long yy = 9 + j;
    wn[j] = fabsf(Lc[yy * W] - Rc[yy * W]);
  }
  TILE_FULL();
  Ob[0]   = oc_[14];
  Ob[W64] = oc_[15] - oc_[0];
  ROT();

#pragma unroll 1
  for (int tt = 1; tt <= 32; ++tt) {
#pragma unroll
    for (int j = 0; j < 16; ++j) {
      const long yy = 16 * (tt + 1) + j - 7;
      wn[j] = fabsf(Lc[yy * W] - Rc[yy * W]);
    }
    TILE_FULL();
#pragma unroll
    for (int j = 0; j < 16; ++j) {
      const float lo = (j < 15) ? op_[j + 1] : oc_[0];
      const long e = 16 * tt + j - 14;
      Ob[e * W64] = oc_[j] - lo;
    }
    ROT();
  }

#pragma unroll
  for (int j = 0; j < 16; ++j) {
    const long yy = 537 + j;
    wn[j] = (j <= 6) ? fabsf(Lc[yy * W] - Rc[yy * W]) : 0.f;
  }
  TILE_FULL();
#pragma unroll
  for (int j = 0; j < 16; ++j) {
    const float lo = (j < 15) ? op_[j + 1] : oc_[0];
    const long e = 16 * 33 + j - 14;
    Ob[e * W64] = oc_[j] - lo;
  }
  ROT();

  TILE_PART14();
#pragma unroll
  for (int j = 0; j < 14; ++j) {
    const long e = 530 + j;
    Ob[e * W64] = oc_[j] - op_[j + 1];
  }
}

// ---------------------------------------------------------------------------
// Phase 2: horizontal box + argmin. Block = (y, b), 8 waves (512 thr); lane=d.
// Wave w owns tiles [8w, 8w+8) for w<5, [40+7(w-5), +7) for w>=5 (61 total).
// Same two-phase fold/replay machinery as r15/r16 (verified bitwise); only
// ownership boundaries changed. 4 blocks/CU => 32 waves/CU (full occupancy).
// ---------------------------------------------------------------------------
__global__ __launch_bounds__(512) void hbox_p8(
    const float* __restrict__ out1, int* __restrict__ out) {
  __shared__ float T[61][64];
  const int lane = threadIdx.x & 63;
  const int w    = threadIdx.x >> 6;
  const int y = blockIdx.x, b = blockIdx.y;
  const float* __restrict__ rowp = out1 + ((long)(b * H + y)) * W64 + lane;
  int* __restrict__ orow = out + (long)b * SL + (long)y * W;

  auto val = [&](int q) -> float {
    const int xsrc = q - 7;
    return (xsrc >= 0 && xsrc < W) ? rowp[(long)xsrc * 64] : 0.f;
  };

  const int t0   = (w < 5) ? 8 * w : 40 + 7 * (w - 5);   // 0,8,16,24,32,40,47,54
  const int tend = t0 + ((w < 5) ? 8 : 7);

  // ---- phase A: owned-tile totals (identical 16-add order) ----
  for (int t = t0; t < tend; ++t) {
    float vv[16];
#pragma unroll
    for (int j = 0; j < 16; ++j) vv[j] = val(16 * t + j);
    float s = vv[0];
#pragma unroll
    for (int j = 1; j < 16; ++j) s += vv[j];
    T[t][lane] = s;
  }
  __syncthreads();

  // ---- phase B: replay fold to entry state ----
  float o1p = 0.f, o2 = 0.f;
  int c = 0, a = 0;
  for (int tp = 0; tp + 1 < t0; ++tp) fold16(o1p, o2, c, a, T[tp][lane]);

  float poc[16];
  if (w > 0) {                                     // recompute tile t0-1 scan
    const float base_prev = baseof(o1p, o2, c, a);
    fold16(o1p, o2, c, a, T[t0 - 1][lane]);
    float vv[16];
#pragma unroll
    for (int j = 0; j < 16; ++j) vv[j] = val(16 * (t0 - 1) + j);
    float ipp = vv[0];
    poc[0] = base_prev + ipp;
#pragma unroll
    for (int j = 1; j < 16; ++j) { ipp += vv[j]; poc[j] = base_prev + ipp; }
  }
  float base = baseof(o1p, o2, c, a);

  for (int t = t0; t < tend; ++t) {
    float vv[16];
#pragma unroll
    for (int j = 0; j < 16; ++j) vv[j] = val(16 * t + j);
    float oc_[16];
    float ip = vv[0];
    oc_[0] = base + ip;
#pragma unroll
    for (int j = 1; j < 16; ++j) { ip += vv[j]; oc_[j] = base + ip; }

    if (t == 0) {
      const float c0 = oc_[14], c1 = oc_[15] - oc_[0];   // e = 0, 1
      float m0 = c0, m1 = c1;
#pragma unroll
      for (int s = 0; s < 6; ++s) {
        const int off = 1 << s;
        m0 = fminf(m0, __shfl_xor(m0, off));
        m1 = fminf(m1, __shfl_xor(m1, off));
      }
      const int d0 = __ffsll((unsigned long long)__ballot(c0 == m0)) - 1;
      const int d1 = __ffsll((unsigned long long)__ballot(c1 == m1)) - 1;
      const int res = (lane == 0) ? d0 : d1;
      if (lane < 2) orow[lane] = res;
    } else if (t == 60) {                          // partial: e = 946..959
      float bc[14], mn[14];
#pragma unroll
      for (int j = 0; j < 14; ++j) { bc[j] = oc_[j] - poc[j + 1]; mn[j] = bc[j]; }
#pragma unroll
      for (int s = 0; s < 6; ++s) {
        const int off = 1 << s;
#pragma unroll
        for (int j = 0; j < 14; ++j) mn[j] = fminf(mn[j], __shfl_xor(mn[j], off));
      }
      int res = 0;
#pragma unroll
      for (int j = 0; j < 14; ++j) {
        const int dj = __ffsll((unsigned long long)__ballot(bc[j] == mn[j])) - 1;
        res = (lane == j) ? dj : res;
      }
      if (lane < 14) orow[946 + lane] = res;
    } else {
      float bc[16], mn[16];
#pragma unroll
      for (int j = 0; j < 16; ++j) {
        bc[j] = oc_[j] - ((j < 15) ? poc[j + 1] : oc_[0]);
        mn[j] = bc[j];
      }
#pragma unroll
      for (int s = 0; s < 6; ++s) {
        const int off = 1 << s;
#pragma unroll
        for (int j = 0; j < 16; ++j) mn[j] = fminf(mn[j], __shfl_xor(mn[j], off));
      }
      int res = 0;
#pragma unroll
      for (int j = 0; j < 16; ++j) {
        const int dj = __ffsll((unsigned long long)__ballot(bc[j] == mn[j])) - 1;
        res = (lane == j) ? dj : res;
      }
      if (lane < 16) orow[16 * t - 14 + lane] = res;
    }

    if (t + 1 < tend) {
      fold16(o1p, o2, c, a, ip);
      base = baseof(o1p, o2, c, a);
#pragma unroll
      for (int j = 0; j < 16; ++j) poc[j] = oc_[j];
    }
  }
}

extern "C" void kernel_launch(void* const* d_in, const int* in_sizes, int n_in,
                              void* d_out, int out_size, void* d_ws, size_t ws_size,
                              hipStream_t stream) {
  const float* L = (const float*)d_in[0];
  const float* R = (const float*)d_in[1];
  int* out = (int*)d_out;
  if (ws_size < (size_t)(D * SLICE_B)) return;   // direct path confirmed in r12
  float* out1 = (float*)d_ws;

  vbox_t<<<(NB * W * 64) / 256, 256, 0, stream>>>(L, R, out1);
  hbox_p8<<<dim3(H, NB), 512, 0, stream>>>(out1, out);
}